// Round 8
// baseline (2650.570 us; speedup 1.0000x reference)
//
#include <hip/hip_runtime.h>
#include <stdint.h>

// Round 8: TWO matrices per 640-thread WG, interleaved in the same threads.
// r7 evidence: exactly 1 WG/CU ever resident (occupancy == WG waves each round),
// VALUBusy 55.7% -> latency bubbles. Fix: 2x independent work between barriers.
// Each thread owns KtA[3][13] + KtB[3][13] (78 VGPR; 640-thr allocator is
// pressure-driven, budget ~170 at 10 waves). Row pass: 6 independent dot2
// chains. Col pass: 4 independent reduction trees per k2. Combine A (tid<100,
// waves 0-1) runs concurrently with combine B (tid 320-419, waves 5-6).
// Build: bufA/bufB 64KB double-buffer, bands A0,B0,A1,B1,A2,B2 with counted
// vmcnt(7) - one stage always in flight under exp/pack compute.
// scr/bbp overlay dead staging buffers after build; LDS = 128,000 B.

#define NN 200
#define NMAT 2560
#define NITER 20

// LDS layout (u32 units)
#define BUFB_OFF 16000
#define SCRA_OFF 0       // overlay on bufA after build
#define SCRB_OFF 2080
#define BBPA_OFF 4160
#define BBPB_OFF 4264
#define WRED_OFF 4368
#define SM_U32 32000     // 128,000 bytes

typedef uint32_t u32;

__device__ __forceinline__ float blo(u32 u){ return __uint_as_float(u<<16); }
__device__ __forceinline__ float bhi(u32 u){ return __uint_as_float(u & 0xffff0000u); }
__device__ __forceinline__ u32 bpack(float lo, float hi){
  u32 a=__float_as_uint(lo); a += 0x7fffu + ((a>>16)&1u);
  u32 b=__float_as_uint(hi); b += 0x7fffu + ((b>>16)&1u);
  return (a>>16) | (b & 0xffff0000u);
}
__device__ __forceinline__ float dot2bf(u32 kp, u32 bp, float acc){
  asm("v_dot2_f32_bf16 %0, %1, %2, %0" : "+v"(acc) : "v"(kp), "v"(bp));
  return acc;
}
template<int CTRL>
__device__ __forceinline__ float dpp_add(float x){
  return x + __int_as_float(__builtin_amdgcn_update_dpp(0, __float_as_int(x), CTRL, 0xF, 0xF, true));
}
template<int PAT>
__device__ __forceinline__ float swz_add(float x){
  return x + __int_as_float(__builtin_amdgcn_ds_swizzle(__float_as_int(x), PAT));
}
__device__ __forceinline__ float pl16_add(float x){
#if __has_builtin(__builtin_amdgcn_permlane16_swap)
  auto r = __builtin_amdgcn_permlane16_swap(__float_as_uint(x), __float_as_uint(x), false, false);
  return __uint_as_float(r[0]) + __uint_as_float(r[1]);
#else
  return x + __shfl_xor(x, 16, 64);
#endif
}
__device__ __forceinline__ float pl32_add(float x){
#if __has_builtin(__builtin_amdgcn_permlane32_swap)
  auto r = __builtin_amdgcn_permlane32_swap(__float_as_uint(x), __float_as_uint(x), false, false);
  return __uint_as_float(r[0]) + __uint_as_float(r[1]);
#else
  return x + __shfl_xor(x, 32, 64);
#endif
}

// ---------------- prep: piecewise-affine MLP coefficients ------------------
// ws layout (f32): [0..32) knots (unsorted); [32..) AB[33][200][2] interleaved.
__global__ void __launch_bounds__(256)
prep_kernel(const float* __restrict__ W1, const float* __restrict__ b1,
            const float* __restrict__ W2, const float* __restrict__ b2,
            float* __restrict__ ws) {
  __shared__ float kn[32], sg[32], w1s[32], b1s[32];
  __shared__ int ord[32];
  const int tid = threadIdx.x;
  if (tid < 32) {
    const float w1 = W1[tid], bv = b1[tid];
    float knot, s;
    if (w1 != 0.f) { knot = -bv / w1; s = (w1 > 0.f) ? 1.f : -1.f; }
    else           { knot = (bv > 0.f) ? -1e30f : 1e30f; s = 1.f; }
    kn[tid] = knot; sg[tid] = s; w1s[tid] = w1; b1s[tid] = bv;
    ws[tid] = knot;
  }
  __syncthreads();
  if (tid < 32) {
    int rk = 0;
#pragma unroll
    for (int v = 0; v < 32; ++v) {
      const float kv = kn[v];
      rk += (kv < kn[tid] || (kv == kn[tid] && v < tid)) ? 1 : 0;
    }
    ord[rk] = tid;
  }
  __syncthreads();
  if (tid < NN) {
    float w2l[32];
#pragma unroll
    for (int u = 0; u < 32; ++u) w2l[u] = W2[tid*32 + u];
    float A = 0.f, Bv = b2[tid];
#pragma unroll
    for (int u = 0; u < 32; ++u)
      if (sg[u] < 0.f) { A += w2l[u]*w1s[u]; Bv += w2l[u]*b1s[u]; }
    float* AB = ws + 32;
    AB[(0*NN + tid)*2 + 0] = A;
    AB[(0*NN + tid)*2 + 1] = Bv;
    for (int s = 0; s < 32; ++s) {
      const int u = ord[s];
      A  += sg[u]*w2l[u]*w1s[u];
      Bv += sg[u]*w2l[u]*b1s[u];
      AB[((s+1)*NN + tid)*2 + 0] = A;
      AB[((s+1)*NN + tid)*2 + 1] = Bv;
    }
  }
}

// ---------------- main ------------------------------------------------------
__global__ void __launch_bounds__(640)
sinkhorn_main(const float* __restrict__ random_,    // [256*200]
              const float* __restrict__ ordered_t,  // [2560*200]
              const float* __restrict__ random_t,   // [2560*200]
              const float* __restrict__ gumbel,     // [2560*200*200]
              const float* __restrict__ ws,
              float* __restrict__ out) {
  extern __shared__ u32 sm[];
  u32* bufA = sm;
  u32* bufB = sm + BUFB_OFF;
  float* scrA = (float*)(sm + SCRA_OFF);
  float* scrB = (float*)(sm + SCRB_OFF);
  u32* bbpA = sm + BBPA_OFF;
  u32* bbpB = sm + BBPB_OFF;
  float* wred = (float*)(sm + WRED_OFF);

  const int tid  = threadIdx.x;
  const int m0   = blockIdx.x * 2;
  const int m1   = m0 + 1;

  const int w    = tid >> 6;          // 0..9
  const int lane = tid & 63;
  const int cg   = lane & 7;          // bits 0-2
  const int rgl  = (lane >> 3) & 7;   // bits 3-5
  const int rg   = w * 8 + rgl;       // 0..79
  const bool nr3 = (rg < 40);         // wave-uniform (w<5)
  const int nr   = nr3 ? 3 : 2;
  const int cbase = 25*cg + (cg & 1); // {0,26,50,76,100,126,150,176}
  const int csz   = 26 - 2*(cg & 1);  // 26 even cg, 24 odd cg
  const int p0    = cbase >> 1;

  float xrA[3], xrB[3]; int iiA[3], iiB[3];
#pragma unroll
  for (int d = 0; d < 3; ++d) { xrA[d]=0.f; xrB[d]=0.f; iiA[d]=0; iiB[d]=0; }
#pragma unroll
  for (int d = 0; d < 3; ++d)
    if (d < nr) {
      xrA[d] = random_[(m0 & 255)*NN + 80*d + rg];
      xrB[d] = random_[(m1 & 255)*NN + 80*d + rg];
    }
  for (int u = 0; u < 32; ++u) {
    const float kn = ws[u];
#pragma unroll
    for (int d = 0; d < 3; ++d) {
      iiA[d] += (kn < xrA[d]) ? 1 : 0;
      iiB[d] += (kn < xrB[d]) ? 1 : 0;
    }
  }

  const float* ABt = ws + 32;
  const char* gA = (const char*)gumbel + (size_t)m0 * (NN*NN*4);
  const char* gB = (const char*)gumbel + (size_t)m1 * (NN*NN*4);

  u32 KtA[3][13], KtB[3][13];

#define ISSUE(G, D, BUF) do { \
    const char* gsrc_ = (G) + (D)*64000 + w*6400; \
    u32* dst_ = (BUF) + w*1600; \
    _Pragma("unroll") \
    for (int i_ = 0; i_ < 6; ++i_) \
      __builtin_amdgcn_global_load_lds((const u32*)(gsrc_ + i_*1024 + lane*16), \
                                       dst_ + i_*256, 16, 0, 0); \
    __builtin_amdgcn_global_load_lds((const u32*)(gsrc_ + 6144 + lane*4), \
                                     dst_ + 1536, 4, 0, 0); \
  } while(0)

#define VMW(N) asm volatile("s_waitcnt vmcnt(" #N ")" ::: "memory")
#define LGKM0  asm volatile("s_waitcnt lgkmcnt(0)" ::: "memory")

#define BUILDB(KT, D, BUF, X, IDX) do { \
    const float x_ = (X); \
    const float* ab_ = ABt + (size_t)((IDX)*NN + cbase) * 2; \
    const u32* gls_ = (BUF) + w*1600 + rgl*200 + cbase; \
    _Pragma("unroll") \
    for (int k_ = 0; k_ < 13; ++k_) { \
      u32 pk_ = 0; \
      if (2*k_ < csz) { \
        const float4 abv_ = *(const float4*)(ab_ + 4*k_); \
        const float2 gv_  = *(const float2*)(gls_ + 2*k_); \
        const float e0_ = __expf(fmaf(x_, abv_.x, abv_.y) + gv_.x); \
        const float e1_ = __expf(fmaf(x_, abv_.z, abv_.w) + gv_.y); \
        pk_ = bpack(e0_, e1_); \
      } \
      KT[D][k_] = pk_; \
    } \
  } while(0)

  // ---- build pipeline: one stage always in flight -------------------------
  ISSUE(gA, 0, bufA);
  ISSUE(gB, 0, bufB);
  VMW(7);  BUILDB(KtA, 0, bufA, xrA[0], iiA[0]);
  LGKM0;   ISSUE(gA, 1, bufA);
  VMW(7);  BUILDB(KtB, 0, bufB, xrB[0], iiB[0]);
  LGKM0;   ISSUE(gB, 1, bufB);
  VMW(7);  BUILDB(KtA, 1, bufA, xrA[1], iiA[1]);
  if (nr3) {
    LGKM0;   ISSUE(gA, 2, bufA);
    VMW(7);  BUILDB(KtB, 1, bufB, xrB[1], iiB[1]);
    LGKM0;   ISSUE(gB, 2, bufB);
    VMW(7);  BUILDB(KtA, 2, bufA, xrA[2], iiA[2]);
    VMW(0);  BUILDB(KtB, 2, bufB, xrB[2], iiB[2]);
  } else {
    VMW(0);  BUILDB(KtB, 1, bufB, xrB[1], iiB[1]);
#pragma unroll
    for (int k = 0; k < 13; ++k) { KtA[2][k] = 0; KtB[2][k] = 0; }
  }
  __syncthreads();   // staging buffers now dead; overlay scr/bbp
  if (tid < 104) bbpA[tid] = 0x3f803f80u;
  if (tid >= 320 && tid < 424) bbpB[tid - 320] = 0x3f803f80u;
  __syncthreads();

  // pair-thread mapping: A on tid<100, B on tid in [320,420)
  const bool ispA = (tid < 100);
  const bool ispB = (tid >= 320 && tid < 420);
  const int t2 = ispB ? (tid - 320) : tid;
  int pscr = 0;
  if (ispA || ispB) {
    const int col = 2*t2;
    int gq = col / 25;
    if (col < 25*gq + (gq&1)) --gq;
    pscr = gq*13 + ((col - (25*gq + (gq&1))) >> 1);
  }

  // ------- 20 multiplicative Sinkhorn iterations (A and B interleaved) -----
  float a0A, a1A, a2A, a0B, a1B, a2B;
  float b0rA = 1.f, b1rA = 1.f, b0rB = 1.f, b1rB = 1.f;

  for (int it = 0; it < NITER; ++it) {
    // row pass: 6 independent dot2 chains
    float c0A=0.f,c1A=0.f,c2A=0.f, c0B=0.f,c1B=0.f,c2B=0.f;
#pragma unroll
    for (int k = 0; k < 13; ++k) {
      const u32 bpA = bbpA[p0 + k];
      const u32 bpB = bbpB[p0 + k];
      c0A = dot2bf(KtA[0][k], bpA, c0A);
      c1A = dot2bf(KtA[1][k], bpA, c1A);
      c2A = dot2bf(KtA[2][k], bpA, c2A);
      c0B = dot2bf(KtB[0][k], bpB, c0B);
      c1B = dot2bf(KtB[1][k], bpB, c1B);
      c2B = dot2bf(KtB[2][k], bpB, c2B);
    }
    c0A = swz_add<0x101F>(dpp_add<0x4E>(dpp_add<0xB1>(c0A)));
    c1A = swz_add<0x101F>(dpp_add<0x4E>(dpp_add<0xB1>(c1A)));
    c2A = swz_add<0x101F>(dpp_add<0x4E>(dpp_add<0xB1>(c2A)));
    c0B = swz_add<0x101F>(dpp_add<0x4E>(dpp_add<0xB1>(c0B)));
    c1B = swz_add<0x101F>(dpp_add<0x4E>(dpp_add<0xB1>(c1B)));
    c2B = swz_add<0x101F>(dpp_add<0x4E>(dpp_add<0xB1>(c2B)));
    a0A = __builtin_amdgcn_rcpf(c0A);
    a1A = __builtin_amdgcn_rcpf(c1A);
    a2A = nr3 ? __builtin_amdgcn_rcpf(c2A) : 0.f;
    a0B = __builtin_amdgcn_rcpf(c0B);
    a1B = __builtin_amdgcn_rcpf(c1B);
    a2B = nr3 ? __builtin_amdgcn_rcpf(c2B) : 0.f;

    // col pass: 4 independent reduction trees per k2
#pragma unroll
    for (int k2 = 0; k2 < 13; ++k2) {
      const u32 dA0 = KtA[0][k2], dA1 = KtA[1][k2], dA2 = KtA[2][k2];
      const u32 dB0 = KtB[0][k2], dB1 = KtB[1][k2], dB2 = KtB[2][k2];
      float loA = blo(dA0)*a0A, hiA = bhi(dA0)*a0A;
      float loB = blo(dB0)*a0B, hiB = bhi(dB0)*a0B;
      loA = fmaf(blo(dA1), a1A, loA); hiA = fmaf(bhi(dA1), a1A, hiA);
      loB = fmaf(blo(dB1), a1B, loB); hiB = fmaf(bhi(dB1), a1B, hiB);
      loA = fmaf(blo(dA2), a2A, loA); hiA = fmaf(bhi(dA2), a2A, hiA);
      loB = fmaf(blo(dB2), a2B, loB); hiB = fmaf(bhi(dB2), a2B, hiB);
      loA = pl32_add(pl16_add(dpp_add<0x128>(loA)));
      hiA = pl32_add(pl16_add(dpp_add<0x128>(hiA)));
      loB = pl32_add(pl16_add(dpp_add<0x128>(loB)));
      hiB = pl32_add(pl16_add(dpp_add<0x128>(hiB)));
      if ((lane & 56) == 0) {
        *(float2*)(scrA + (w*104 + cg*13 + k2)*2) = make_float2(loA, hiA);
        *(float2*)(scrB + (w*104 + cg*13 + k2)*2) = make_float2(loB, hiB);
      }
    }
    __syncthreads();
    if (ispA) {
      float s0 = 0.f, s1 = 0.f;
#pragma unroll
      for (int ww = 0; ww < 10; ++ww) {
        const float2 v = *(const float2*)(scrA + (ww*104 + pscr)*2);
        s0 += v.x; s1 += v.y;
      }
      b0rA = __builtin_amdgcn_rcpf(s0);
      b1rA = __builtin_amdgcn_rcpf(s1);
      bbpA[t2] = bpack(b0rA, b1rA);
    } else if (ispB) {
      float s0 = 0.f, s1 = 0.f;
#pragma unroll
      for (int ww = 0; ww < 10; ++ww) {
        const float2 v = *(const float2*)(scrB + (ww*104 + pscr)*2);
        s0 += v.x; s1 += v.y;
      }
      b0rB = __builtin_amdgcn_rcpf(s0);
      b1rB = __builtin_amdgcn_rcpf(s1);
      bbpB[t2] = bpack(b0rB, b1rB);
    }
    __syncthreads();
  }

  // ------- loss: rec = b .* K^T(a .* r); mean((ordered - rec)^2) -----------
  const float ar0A = a0A * random_t[m0*NN + rg];
  const float ar1A = a1A * random_t[m0*NN + 80 + rg];
  const float ar2A = nr3 ? a2A * random_t[m0*NN + 160 + rg] : 0.f;
  const float ar0B = a0B * random_t[m1*NN + rg];
  const float ar1B = a1B * random_t[m1*NN + 80 + rg];
  const float ar2B = nr3 ? a2B * random_t[m1*NN + 160 + rg] : 0.f;
#pragma unroll
  for (int k2 = 0; k2 < 13; ++k2) {
    const u32 dA0 = KtA[0][k2], dA1 = KtA[1][k2], dA2 = KtA[2][k2];
    const u32 dB0 = KtB[0][k2], dB1 = KtB[1][k2], dB2 = KtB[2][k2];
    float loA = blo(dA0)*ar0A, hiA = bhi(dA0)*ar0A;
    float loB = blo(dB0)*ar0B, hiB = bhi(dB0)*ar0B;
    loA = fmaf(blo(dA1), ar1A, loA); hiA = fmaf(bhi(dA1), ar1A, hiA);
    loB = fmaf(blo(dB1), ar1B, loB); hiB = fmaf(bhi(dB1), ar1B, hiB);
    loA = fmaf(blo(dA2), ar2A, loA); hiA = fmaf(bhi(dA2), ar2A, hiA);
    loB = fmaf(blo(dB2), ar2B, loB); hiB = fmaf(bhi(dB2), ar2B, hiB);
    loA = pl32_add(pl16_add(dpp_add<0x128>(loA)));
    hiA = pl32_add(pl16_add(dpp_add<0x128>(hiA)));
    loB = pl32_add(pl16_add(dpp_add<0x128>(loB)));
    hiB = pl32_add(pl16_add(dpp_add<0x128>(hiB)));
    if ((lane & 56) == 0) {
      *(float2*)(scrA + (w*104 + cg*13 + k2)*2) = make_float2(loA, hiA);
      *(float2*)(scrB + (w*104 + cg*13 + k2)*2) = make_float2(loB, hiB);
    }
  }
  __syncthreads();
  float lacc = 0.f;
  if (ispA) {
    float s0 = 0.f, s1 = 0.f;
#pragma unroll
    for (int ww = 0; ww < 10; ++ww) {
      const float2 v = *(const float2*)(scrA + (ww*104 + pscr)*2);
      s0 += v.x; s1 += v.y;
    }
    const float2 ov = *(const float2*)(ordered_t + m0*NN + 2*t2);
    const float d0 = ov.x - b0rA*s0;
    const float d1 = ov.y - b1rA*s1;
    lacc = fmaf(d0, d0, d1*d1);
  } else if (ispB) {
    float s0 = 0.f, s1 = 0.f;
#pragma unroll
    for (int ww = 0; ww < 10; ++ww) {
      const float2 v = *(const float2*)(scrB + (ww*104 + pscr)*2);
      s0 += v.x; s1 += v.y;
    }
    const float2 ov = *(const float2*)(ordered_t + m1*NN + 2*t2);
    const float d0 = ov.x - b0rB*s0;
    const float d1 = ov.y - b1rB*s1;
    lacc = fmaf(d0, d0, d1*d1);
  }
  if (w < 2 || w == 5 || w == 6) {
    lacc = dpp_add<0xB1>(lacc);
    lacc = dpp_add<0x4E>(lacc);
    lacc = swz_add<0x101F>(lacc);
    lacc = dpp_add<0x128>(lacc);
    lacc = pl16_add(lacc);
    lacc = pl32_add(lacc);
    if (lane == 0) wred[(w < 2) ? w : (w - 3)] = lacc;
  }
  __syncthreads();
  if (tid == 0)
    atomicAdd(out, (wred[0] + wred[1] + wred[2] + wred[3]) * (1.0f / 512000.0f));
}

extern "C" void kernel_launch(void* const* d_in, const int* in_sizes, int n_in,
                              void* d_out, int out_size, void* d_ws, size_t ws_size,
                              hipStream_t stream) {
  (void)in_sizes; (void)n_in; (void)ws_size; (void)out_size;
  const float* random_  = (const float*)d_in[0];
  const float* ordered  = (const float*)d_in[1];
  const float* random_t = (const float*)d_in[2];
  const float* gumbel   = (const float*)d_in[3];
  const float* W1 = (const float*)d_in[4];
  const float* b1 = (const float*)d_in[5];
  const float* W2 = (const float*)d_in[6];
  const float* b2 = (const float*)d_in[7];
  float* out = (float*)d_out;
  float* ws  = (float*)d_ws;   // needs 52,928 B

  const size_t smem = SM_U32 * sizeof(u32);  // 128,000 B
  hipFuncSetAttribute((const void*)sinkhorn_main,
                      hipFuncAttributeMaxDynamicSharedMemorySize, (int)smem);
  prep_kernel<<<1, 256, 0, stream>>>(W1, b1, W2, b2, ws);
  hipMemsetAsync(out, 0, sizeof(float), stream);
  sinkhorn_main<<<NMAT/2, 640, smem, stream>>>(random_, ordered, random_t, gumbel, ws, out);
}

// Round 9
// 667.174 us; speedup vs baseline: 3.9728x; 3.9728x over previous
//
#include <hip/hip_runtime.h>
#include <stdint.h>

// Round 9: co-residency experiment. r7 kept only 1 WG/CU resident (occupancy
// 29.7%) despite 2 WGs fitting LDS+VGPR on paper; every kernel since r2 used
// >64KB LDS/WG. Test: drop LDS staging entirely -> per-thread register staging
// of gumbel (13 x float2, contiguous 104B/thread), LDS shrinks to 8.8KB static.
// If large-LDS was the blocker, occupancy -> ~60% (2 WGs, 20 waves/CU).
// Everything else identical to r7 (640 thr, 80 rg x 8 cg, Kt[3][13] bf16 packs,
// dot2 row pass, all-VALU col reduce, 100 pair-thread combine).

#define NN 200
#define NMAT 2560
#define NITER 20

typedef uint32_t u32;

__device__ __forceinline__ float blo(u32 u){ return __uint_as_float(u<<16); }
__device__ __forceinline__ float bhi(u32 u){ return __uint_as_float(u & 0xffff0000u); }
__device__ __forceinline__ u32 bpack(float lo, float hi){
  u32 a=__float_as_uint(lo); a += 0x7fffu + ((a>>16)&1u);
  u32 b=__float_as_uint(hi); b += 0x7fffu + ((b>>16)&1u);
  return (a>>16) | (b & 0xffff0000u);
}
__device__ __forceinline__ float dot2bf(u32 kp, u32 bp, float acc){
  asm("v_dot2_f32_bf16 %0, %1, %2, %0" : "+v"(acc) : "v"(kp), "v"(bp));
  return acc;
}
template<int CTRL>
__device__ __forceinline__ float dpp_add(float x){
  return x + __int_as_float(__builtin_amdgcn_update_dpp(0, __float_as_int(x), CTRL, 0xF, 0xF, true));
}
template<int PAT>
__device__ __forceinline__ float swz_add(float x){
  return x + __int_as_float(__builtin_amdgcn_ds_swizzle(__float_as_int(x), PAT));
}
__device__ __forceinline__ float pl16_add(float x){
#if __has_builtin(__builtin_amdgcn_permlane16_swap)
  auto r = __builtin_amdgcn_permlane16_swap(__float_as_uint(x), __float_as_uint(x), false, false);
  return __uint_as_float(r[0]) + __uint_as_float(r[1]);
#else
  return x + __shfl_xor(x, 16, 64);
#endif
}
__device__ __forceinline__ float pl32_add(float x){
#if __has_builtin(__builtin_amdgcn_permlane32_swap)
  auto r = __builtin_amdgcn_permlane32_swap(__float_as_uint(x), __float_as_uint(x), false, false);
  return __uint_as_float(r[0]) + __uint_as_float(r[1]);
#else
  return x + __shfl_xor(x, 32, 64);
#endif
}

// ---------------- prep: piecewise-affine MLP coefficients ------------------
// ws layout (f32): [0..32) knots (unsorted); [32..) AB[33][200][2] interleaved.
__global__ void __launch_bounds__(256)
prep_kernel(const float* __restrict__ W1, const float* __restrict__ b1,
            const float* __restrict__ W2, const float* __restrict__ b2,
            float* __restrict__ ws) {
  __shared__ float kn[32], sg[32], w1s[32], b1s[32];
  __shared__ int ord[32];
  const int tid = threadIdx.x;
  if (tid < 32) {
    const float w1 = W1[tid], bv = b1[tid];
    float knot, s;
    if (w1 != 0.f) { knot = -bv / w1; s = (w1 > 0.f) ? 1.f : -1.f; }
    else           { knot = (bv > 0.f) ? -1e30f : 1e30f; s = 1.f; }
    kn[tid] = knot; sg[tid] = s; w1s[tid] = w1; b1s[tid] = bv;
    ws[tid] = knot;
  }
  __syncthreads();
  if (tid < 32) {
    int rk = 0;
#pragma unroll
    for (int v = 0; v < 32; ++v) {
      const float kv = kn[v];
      rk += (kv < kn[tid] || (kv == kn[tid] && v < tid)) ? 1 : 0;
    }
    ord[rk] = tid;
  }
  __syncthreads();
  if (tid < NN) {
    float w2l[32];
#pragma unroll
    for (int u = 0; u < 32; ++u) w2l[u] = W2[tid*32 + u];
    float A = 0.f, Bv = b2[tid];
#pragma unroll
    for (int u = 0; u < 32; ++u)
      if (sg[u] < 0.f) { A += w2l[u]*w1s[u]; Bv += w2l[u]*b1s[u]; }
    float* AB = ws + 32;
    AB[(0*NN + tid)*2 + 0] = A;
    AB[(0*NN + tid)*2 + 1] = Bv;
    for (int s = 0; s < 32; ++s) {
      const int u = ord[s];
      A  += sg[u]*w2l[u]*w1s[u];
      Bv += sg[u]*w2l[u]*b1s[u];
      AB[((s+1)*NN + tid)*2 + 0] = A;
      AB[((s+1)*NN + tid)*2 + 1] = Bv;
    }
  }
}

// ---------------- main ------------------------------------------------------
__global__ void __launch_bounds__(640)
sinkhorn_main(const float* __restrict__ random_,    // [256*200]
              const float* __restrict__ ordered_t,  // [2560*200]
              const float* __restrict__ random_t,   // [2560*200]
              const float* __restrict__ gumbel,     // [2560*200*200]
              const float* __restrict__ ws,
              float* __restrict__ out) {
  __shared__ float scr[10*104*2];   // [wave][cg*13+k2][2]
  __shared__ u32 bbp[104];          // packed bf16 b-pairs
  __shared__ float wred[4];

  const int tid  = threadIdx.x;
  const int m    = blockIdx.x;
  const int bidx = m & 255;

  const int w    = tid >> 6;          // 0..9
  const int lane = tid & 63;
  const int cg   = lane & 7;          // bits 0-2
  const int rgl  = (lane >> 3) & 7;   // bits 3-5
  const int rg   = w * 8 + rgl;       // 0..79; owns rows {80d + rg : d < nr}
  const bool nr3 = (rg < 40);         // wave-uniform (w<5)
  const int nr   = nr3 ? 3 : 2;
  const int cbase = 25*cg + (cg & 1); // {0,26,50,76,100,126,150,176}
  const int csz   = 26 - 2*(cg & 1);  // 26 even cg, 24 odd cg
  const int p0    = cbase >> 1;

  if (tid < 104) bbp[tid] = 0x3f803f80u;  // packed {1.0bf, 1.0bf}
  __syncthreads();

  float xr[3]; int ii[3];
#pragma unroll
  for (int d = 0; d < 3; ++d) { xr[d] = 0.f; ii[d] = 0; }
#pragma unroll
  for (int d = 0; d < 3; ++d)
    if (d < nr) xr[d] = random_[bidx*NN + 80*d + rg];
  for (int u = 0; u < 32; ++u) {
    const float kn = ws[u];
#pragma unroll
    for (int d = 0; d < 3; ++d) ii[d] += (kn < xr[d]) ? 1 : 0;
  }

  const float* ABt = ws + 32;
  const float* gmat = gumbel + (size_t)m * (NN*NN);

  u32 Kt[3][13];

  // ------- build: per-thread register staging (no LDS) ---------------------
#pragma unroll
  for (int d = 0; d < 3; ++d) {
    if (d < nr) {
      const float* grow = gmat + (size_t)(80*d + rg)*NN + cbase;
      float2 g[13];
#pragma unroll
      for (int k = 0; k < 13; ++k)
        g[k] = (2*k < csz) ? *(const float2*)(grow + 2*k) : make_float2(0.f, 0.f);
      const float x = xr[d];
      const float* ab = ABt + (size_t)(ii[d]*NN + cbase) * 2;
#pragma unroll
      for (int k = 0; k < 13; ++k) {
        u32 pk = 0;
        if (2*k < csz) {
          const float4 abv = *(const float4*)(ab + 4*k);   // {A0,B0,A1,B1}
          const float e0 = __expf(fmaf(x, abv.x, abv.y) + g[k].x);
          const float e1 = __expf(fmaf(x, abv.z, abv.w) + g[k].y);
          pk = bpack(e0, e1);
        }
        Kt[d][k] = pk;
      }
    } else {
#pragma unroll
      for (int k = 0; k < 13; ++k) Kt[d][k] = 0;
    }
  }

  // pair-thread mapping: tid<100 owns cols (2*tid, 2*tid+1)
  const bool isp = (tid < 100);
  int pscr = 0;
  if (isp) {
    const int col = 2*tid;
    int gq = col / 25;
    if (col < 25*gq + (gq&1)) --gq;
    pscr = gq*13 + ((col - (25*gq + (gq&1))) >> 1);
  }

  // ------- 20 multiplicative Sinkhorn iterations ---------------------------
  float a0, a1, a2;
  float b0r = 1.f, b1r = 1.f;

  for (int it = 0; it < NITER; ++it) {
    // row pass: a = 1/(K b), b packed bf16, k-outer
    float c0 = 0.f, c1 = 0.f, c2 = 0.f;
#pragma unroll
    for (int k = 0; k < 13; ++k) {
      const u32 bp = bbp[p0 + k];
      c0 = dot2bf(Kt[0][k], bp, c0);
      c1 = dot2bf(Kt[1][k], bp, c1);
      c2 = dot2bf(Kt[2][k], bp, c2);
    }
    c0 = swz_add<0x101F>(dpp_add<0x4E>(dpp_add<0xB1>(c0)));
    c1 = swz_add<0x101F>(dpp_add<0x4E>(dpp_add<0xB1>(c1)));
    c2 = swz_add<0x101F>(dpp_add<0x4E>(dpp_add<0xB1>(c2)));
    a0 = __builtin_amdgcn_rcpf(c0);
    a1 = __builtin_amdgcn_rcpf(c1);
    a2 = nr3 ? __builtin_amdgcn_rcpf(c2) : 0.f;  // Kt[2]=0 for nr==2

    // col pass: b = 1/(K^T a)
#pragma unroll
    for (int k2 = 0; k2 < 13; ++k2) {
      const u32 d0 = Kt[0][k2], d1 = Kt[1][k2], d2 = Kt[2][k2];
      float lo = blo(d0) * a0, hi = bhi(d0) * a0;
      lo = fmaf(blo(d1), a1, lo); hi = fmaf(bhi(d1), a1, hi);
      lo = fmaf(blo(d2), a2, lo); hi = fmaf(bhi(d2), a2, hi);
      lo = pl32_add(pl16_add(dpp_add<0x128>(lo)));
      hi = pl32_add(pl16_add(dpp_add<0x128>(hi)));
      if ((lane & 56) == 0)
        *(float2*)(scr + (w*104 + cg*13 + k2)*2) = make_float2(lo, hi);
    }
    __syncthreads();
    if (isp) {
      float s0 = 0.f, s1 = 0.f;
#pragma unroll
      for (int ww = 0; ww < 10; ++ww) {
        const float2 v = *(const float2*)(scr + (ww*104 + pscr)*2);
        s0 += v.x; s1 += v.y;
      }
      b0r = __builtin_amdgcn_rcpf(s0);
      b1r = __builtin_amdgcn_rcpf(s1);
      bbp[tid] = bpack(b0r, b1r);
    }
    __syncthreads();
  }

  // ------- loss: rec = b .* K^T(a .* r); mean((ordered - rec)^2) -----------
  const float ar0 = a0 * random_t[m*NN + rg];
  const float ar1 = a1 * random_t[m*NN + 80 + rg];
  const float ar2 = nr3 ? a2 * random_t[m*NN + 160 + rg] : 0.f;
#pragma unroll
  for (int k2 = 0; k2 < 13; ++k2) {
    const u32 d0 = Kt[0][k2], d1 = Kt[1][k2], d2 = Kt[2][k2];
    float lo = blo(d0) * ar0, hi = bhi(d0) * ar0;
    lo = fmaf(blo(d1), ar1, lo); hi = fmaf(bhi(d1), ar1, hi);
    lo = fmaf(blo(d2), ar2, lo); hi = fmaf(bhi(d2), ar2, hi);
    lo = pl32_add(pl16_add(dpp_add<0x128>(lo)));
    hi = pl32_add(pl16_add(dpp_add<0x128>(hi)));
    if ((lane & 56) == 0)
      *(float2*)(scr + (w*104 + cg*13 + k2)*2) = make_float2(lo, hi);
  }
  __syncthreads();
  float lacc = 0.f;
  if (isp) {
    float s0 = 0.f, s1 = 0.f;
#pragma unroll
    for (int ww = 0; ww < 10; ++ww) {
      const float2 v = *(const float2*)(scr + (ww*104 + pscr)*2);
      s0 += v.x; s1 += v.y;
    }
    const float2 ov = *(const float2*)(ordered_t + m*NN + 2*tid);
    const float d0 = ov.x - b0r*s0;
    const float d1 = ov.y - b1r*s1;
    lacc = fmaf(d0, d0, d1*d1);
  }
  if (w < 2) {
    lacc = dpp_add<0xB1>(lacc);
    lacc = dpp_add<0x4E>(lacc);
    lacc = swz_add<0x101F>(lacc);
    lacc = dpp_add<0x128>(lacc);
    lacc = pl16_add(lacc);
    lacc = pl32_add(lacc);
    if (lane == 0) wred[w] = lacc;
  }
  __syncthreads();
  if (tid == 0)
    atomicAdd(out, (wred[0] + wred[1]) * (1.0f / 512000.0f));
}

extern "C" void kernel_launch(void* const* d_in, const int* in_sizes, int n_in,
                              void* d_out, int out_size, void* d_ws, size_t ws_size,
                              hipStream_t stream) {
  (void)in_sizes; (void)n_in; (void)ws_size; (void)out_size;
  const float* random_  = (const float*)d_in[0];
  const float* ordered  = (const float*)d_in[1];
  const float* random_t = (const float*)d_in[2];
  const float* gumbel   = (const float*)d_in[3];
  const float* W1 = (const float*)d_in[4];
  const float* b1 = (const float*)d_in[5];
  const float* W2 = (const float*)d_in[6];
  const float* b2 = (const float*)d_in[7];
  float* out = (float*)d_out;
  float* ws  = (float*)d_ws;   // needs 52,928 B

  prep_kernel<<<1, 256, 0, stream>>>(W1, b1, W2, b2, ws);
  hipMemsetAsync(out, 0, sizeof(float), stream);
  sinkhorn_main<<<NMAT, 640, 0, stream>>>(random_, ordered, random_t, gumbel, ws, out);
}

// Round 10
// 493.704 us; speedup vs baseline: 5.3687x; 1.3514x over previous
//
#include <hip/hip_runtime.h>
#include <stdint.h>

// Round 10: symmetric Sinkhorn with K^T staged once in LDS (bf16).
// r9 falsified co-residency (1 WG/CU invariant). r7's loss: col-pass per-k2
// cross-lane trees (130 chained ops/iter) + serial 100-thread combine skew.
// Fix: KtT[col][132 u32] in LDS (528B stride: 16B-aligned b128 reads, banks
// 4*rgl+16*(cg&1) -> 2-way=free). Col pass becomes the SAME shape as row pass:
// 13 contiguous u32 + 39 dot2 + 3-op cg-butterfly + rcp. No trees, no combine.
// Kt[3][13] (row-major bf16 pairs) stays in registers for the row pass.
// 640 thr / 10 waves / 1 matrix per WG. a/b vectors as padded pair arrays
// aap/bbp[8 cg][16] (b128-aligned, pads zeroed; Kt/KtT pads zeroed -> no NaN).

#define NN 200
#define NMAT 2560
#define NITER 20

// LDS layout (u32)
#define KTT_U32 26400    // 200 cols x 132
#define AAP_OFF 26400    // 128
#define BBP_OFF 26528    // 128
#define WRED_OFF 26656   // 16
#define SM_U32 26672     // 106,688 bytes

typedef uint32_t u32;
typedef uint16_t u16;

__device__ __forceinline__ u32 bpack(float lo, float hi){
  u32 a=__float_as_uint(lo); a += 0x7fffu + ((a>>16)&1u);
  u32 b=__float_as_uint(hi); b += 0x7fffu + ((b>>16)&1u);
  return (a>>16) | (b & 0xffff0000u);
}
__device__ __forceinline__ float dot2bf(u32 kp, u32 bp, float acc){
  asm("v_dot2_f32_bf16 %0, %1, %2, %0" : "+v"(acc) : "v"(kp), "v"(bp));
  return acc;
}
template<int CTRL>
__device__ __forceinline__ float dpp_add(float x){
  return x + __int_as_float(__builtin_amdgcn_update_dpp(0, __float_as_int(x), CTRL, 0xF, 0xF, true));
}
template<int PAT>
__device__ __forceinline__ float swz_add(float x){
  return x + __int_as_float(__builtin_amdgcn_ds_swizzle(__float_as_int(x), PAT));
}
__device__ __forceinline__ float xch8(float x){   // value from lane^8 (row_ror:8)
  return __int_as_float(__builtin_amdgcn_update_dpp(0, __float_as_int(x), 0x128, 0xF, 0xF, true));
}
__device__ __forceinline__ float pl16_add(float x){
#if __has_builtin(__builtin_amdgcn_permlane16_swap)
  auto r = __builtin_amdgcn_permlane16_swap(__float_as_uint(x), __float_as_uint(x), false, false);
  return __uint_as_float(r[0]) + __uint_as_float(r[1]);
#else
  return x + __shfl_xor(x, 16, 64);
#endif
}
__device__ __forceinline__ float pl32_add(float x){
#if __has_builtin(__builtin_amdgcn_permlane32_swap)
  auto r = __builtin_amdgcn_permlane32_swap(__float_as_uint(x), __float_as_uint(x), false, false);
  return __uint_as_float(r[0]) + __uint_as_float(r[1]);
#else
  return x + __shfl_xor(x, 32, 64);
#endif
}

// ---------------- prep: piecewise-affine MLP coefficients ------------------
// ws (f32): [0..32) knots (unsorted); [32..) AB[33][200][2] interleaved.
__global__ void __launch_bounds__(256)
prep_kernel(const float* __restrict__ W1, const float* __restrict__ b1,
            const float* __restrict__ W2, const float* __restrict__ b2,
            float* __restrict__ ws) {
  __shared__ float kn[32], sg[32], w1s[32], b1s[32];
  __shared__ int ord[32];
  const int tid = threadIdx.x;
  if (tid < 32) {
    const float w1 = W1[tid], bv = b1[tid];
    float knot, s;
    if (w1 != 0.f) { knot = -bv / w1; s = (w1 > 0.f) ? 1.f : -1.f; }
    else           { knot = (bv > 0.f) ? -1e30f : 1e30f; s = 1.f; }
    kn[tid] = knot; sg[tid] = s; w1s[tid] = w1; b1s[tid] = bv;
    ws[tid] = knot;
  }
  __syncthreads();
  if (tid < 32) {
    int rk = 0;
#pragma unroll
    for (int v = 0; v < 32; ++v) {
      const float kv = kn[v];
      rk += (kv < kn[tid] || (kv == kn[tid] && v < tid)) ? 1 : 0;
    }
    ord[rk] = tid;
  }
  __syncthreads();
  if (tid < NN) {
    float w2l[32];
#pragma unroll
    for (int u = 0; u < 32; ++u) w2l[u] = W2[tid*32 + u];
    float A = 0.f, Bv = b2[tid];
#pragma unroll
    for (int u = 0; u < 32; ++u)
      if (sg[u] < 0.f) { A += w2l[u]*w1s[u]; Bv += w2l[u]*b1s[u]; }
    float* AB = ws + 32;
    AB[(0*NN + tid)*2 + 0] = A;
    AB[(0*NN + tid)*2 + 1] = Bv;
    for (int s = 0; s < 32; ++s) {
      const int u = ord[s];
      A  += sg[u]*w2l[u]*w1s[u];
      Bv += sg[u]*w2l[u]*b1s[u];
      AB[((s+1)*NN + tid)*2 + 0] = A;
      AB[((s+1)*NN + tid)*2 + 1] = Bv;
    }
  }
}

// ---------------- main ------------------------------------------------------
__global__ void __launch_bounds__(640)
sinkhorn_main(const float* __restrict__ random_,    // [256*200]
              const float* __restrict__ ordered_t,  // [2560*200]
              const float* __restrict__ random_t,   // [2560*200]
              const float* __restrict__ gumbel,     // [2560*200*200]
              const float* __restrict__ ws,
              float* __restrict__ out) {
  extern __shared__ u32 sm[];
  u32* KtT = sm;
  u32* aap = sm + AAP_OFF;
  u32* bbp = sm + BBP_OFF;
  float* wred = (float*)(sm + WRED_OFF);

  const int tid  = threadIdx.x;
  const int m    = blockIdx.x;
  const int bidx = m & 255;

  const int w    = tid >> 6;          // 0..9
  const int lane = tid & 63;
  const int cg   = lane & 7;          // bits 0-2: column-chunk group
  const int rgl  = (lane >> 3) & 7;   // bits 3-5
  const int rg   = w * 8 + rgl;       // 0..79
  const bool nr3 = (rg < 40);         // wave-uniform
  const int nr   = nr3 ? 3 : 2;       // rows/cols owned: {80d+rg : d<nr}
  const int cbase = 25*cg + (cg & 1); // even: {0,26,...}; csz 26/24
  const int csz   = 26 - 2*(cg & 1);

  // ---- zero KtT (pads incl. odd-cg slot12) + init vectors ------------------
  {
    const uint4 z = make_uint4(0u,0u,0u,0u);
    for (int i = tid; i < KTT_U32/4; i += 640)
      *(uint4*)(KtT + i*4) = z;
    if (tid < 128) {
      const int npair = 13 - ((tid >> 4) & 1);
      bbp[tid] = ((tid & 15) < npair) ? 0x3f803f80u : 0u;  // {1.0bf,1.0bf}
      aap[tid] = 0u;
    }
  }

  // ---- per-thread pair slots: j = 40d + rg/2 -> padded slot ----------------
  int s0, s1, s2;
  {
    const int jb = rg >> 1;
#pragma unroll
    for (int d = 0; d < 3; ++d) {
      const int j = 40*d + jb;
      const int cgb = (j>=13)+(j>=25)+(j>=38)+(j>=50)+(j>=63)+(j>=75)+(j>=88);
      const int sl = cgb*16 + j - ((25*cgb + (cgb&1)) >> 1);
      if (d == 0) s0 = sl; else if (d == 1) s1 = sl; else s2 = sl;
    }
  }

  // ---- build Kt[3][13] from gumbel (register staging) + MLP affine --------
  float xr[3] = {0.f, 0.f, 0.f}; int ii[3] = {0, 0, 0};
#pragma unroll
  for (int d = 0; d < 3; ++d)
    if (d < nr) xr[d] = random_[bidx*NN + 80*d + rg];
  for (int u = 0; u < 32; ++u) {
    const float kn = ws[u];
#pragma unroll
    for (int d = 0; d < 3; ++d) ii[d] += (kn < xr[d]) ? 1 : 0;
  }
  const float* ABt = ws + 32;
  const float* gmat = gumbel + (size_t)m * (NN*NN);

  u32 Kt[3][13];
#pragma unroll
  for (int d = 0; d < 3; ++d) {
    if (d < nr) {
      const float* grow = gmat + (size_t)(80*d + rg)*NN + cbase;
      float2 g[13];
#pragma unroll
      for (int k = 0; k < 13; ++k)
        g[k] = (2*k < csz) ? *(const float2*)(grow + 2*k) : make_float2(0.f, 0.f);
      const float x = xr[d];
      const float* ab = ABt + (size_t)(ii[d]*NN + cbase) * 2;
#pragma unroll
      for (int k = 0; k < 13; ++k) {
        u32 pk = 0;
        if (2*k < csz) {
          const float4 A = *(const float4*)(ab + 4*k);   // {A0,B0,A1,B1}
          pk = bpack(__expf(fmaf(x, A.x, A.y) + g[k].x),
                     __expf(fmaf(x, A.z, A.w) + g[k].y));
        }
        Kt[d][k] = pk;
      }
    } else {
#pragma unroll
      for (int k = 0; k < 13; ++k) Kt[d][k] = 0;
    }
  }
  __syncthreads();   // zero-fill complete before transpose writes

  // ---- transpose into KtT: col (cbase+2k[+1]), pair-slot s_d, half rg&1 ----
#pragma unroll
  for (int d = 0; d < 3; ++d) {
    if (d < nr) {
      const int sd = (d == 0) ? s0 : (d == 1) ? s1 : s2;
      char* tb = (char*)(KtT + cbase*132 + sd) + (rg & 1)*2;
#pragma unroll
      for (int k = 0; k < 13; ++k) {
        if (2*k < csz) {
          *(u16*)(tb + k*1056)       = (u16)(Kt[d][k] & 0xffffu);
          *(u16*)(tb + k*1056 + 528) = (u16)(Kt[d][k] >> 16);
        }
      }
    }
  }
  __syncthreads();

  // ---- 20 symmetric Sinkhorn iterations ------------------------------------
  const u32* bbv = bbp + cg*16;
  const u32* aav = aap + cg*16;
  float a0, a1, a2 = 0.f, b0 = 1.f, b1 = 1.f, b2 = 1.f;

  for (int it = 0; it < NITER; ++it) {
    // row pass: a_r = 1/sum_c K[r][c] b_c  (K from registers)
    u32 bv[13];
    *(uint4*)&bv[0] = *(const uint4*)(bbv);
    *(uint4*)&bv[4] = *(const uint4*)(bbv + 4);
    *(uint4*)&bv[8] = *(const uint4*)(bbv + 8);
    bv[12] = bbv[12];
    float c0 = 0.f, c1 = 0.f, c2 = 0.f;
#pragma unroll
    for (int k = 0; k < 13; ++k) {
      c0 = dot2bf(Kt[0][k], bv[k], c0);
      c1 = dot2bf(Kt[1][k], bv[k], c1);
      c2 = dot2bf(Kt[2][k], bv[k], c2);
    }
    c0 = swz_add<0x101F>(dpp_add<0x4E>(dpp_add<0xB1>(c0)));
    c1 = swz_add<0x101F>(dpp_add<0x4E>(dpp_add<0xB1>(c1)));
    c2 = swz_add<0x101F>(dpp_add<0x4E>(dpp_add<0xB1>(c2)));
    a0 = __builtin_amdgcn_rcpf(c0);
    a1 = __builtin_amdgcn_rcpf(c1);
    a2 = nr3 ? __builtin_amdgcn_rcpf(c2) : 0.f;
    {
      const float a0s = xch8(a0), a1s = xch8(a1), a2s = xch8(a2);
      if (cg == 0 && !(rg & 1)) {
        aap[s0] = bpack(a0, a0s);
        aap[s1] = bpack(a1, a1s);
        if (nr3) aap[s2] = bpack(a2, a2s);
      }
    }
    __syncthreads();

    // col pass: b_c = 1/sum_r K[r][c] a_r  (K^T from LDS, same shape)
    u32 av[13];
    *(uint4*)&av[0] = *(const uint4*)(aav);
    *(uint4*)&av[4] = *(const uint4*)(aav + 4);
    *(uint4*)&av[8] = *(const uint4*)(aav + 8);
    av[12] = aav[12];
    float e0 = 0.f, e1 = 0.f, e2 = 0.f;
#pragma unroll
    for (int d = 0; d < 3; ++d) {
      if (d < nr) {
        const u32* kc = KtT + (80*d + rg)*132 + cg*16;
        u32 kv[13];
        *(uint4*)&kv[0] = *(const uint4*)(kc);
        *(uint4*)&kv[4] = *(const uint4*)(kc + 4);
        *(uint4*)&kv[8] = *(const uint4*)(kc + 8);
        kv[12] = kc[12];
        float acc = 0.f;
#pragma unroll
        for (int k = 0; k < 13; ++k) acc = dot2bf(kv[k], av[k], acc);
        if (d == 0) e0 = acc; else if (d == 1) e1 = acc; else e2 = acc;
      }
    }
    e0 = swz_add<0x101F>(dpp_add<0x4E>(dpp_add<0xB1>(e0)));
    e1 = swz_add<0x101F>(dpp_add<0x4E>(dpp_add<0xB1>(e1)));
    e2 = swz_add<0x101F>(dpp_add<0x4E>(dpp_add<0xB1>(e2)));
    b0 = __builtin_amdgcn_rcpf(e0);
    b1 = __builtin_amdgcn_rcpf(e1);
    b2 = nr3 ? __builtin_amdgcn_rcpf(e2) : 0.f;
    {
      const float b0s = xch8(b0), b1s = xch8(b1), b2s = xch8(b2);
      if (cg == 0 && !(rg & 1)) {
        bbp[s0] = bpack(b0, b0s);
        bbp[s1] = bpack(b1, b1s);
        if (nr3) bbp[s2] = bpack(b2, b2s);
      }
    }
    __syncthreads();
  }

  // ---- loss: rec_c = b_c * sum_r K[r][c] (a_r * r_r) ------------------------
  {
    const float r0 = a0 * random_t[m*NN + rg];
    const float r1 = a1 * random_t[m*NN + 80 + rg];
    const float r2 = nr3 ? a2 * random_t[m*NN + 160 + rg] : 0.f;
    const float r0s = xch8(r0), r1s = xch8(r1), r2s = xch8(r2);
    if (cg == 0 && !(rg & 1)) {
      aap[s0] = bpack(r0, r0s);
      aap[s1] = bpack(r1, r1s);
      if (nr3) aap[s2] = bpack(r2, r2s);
    }
  }
  __syncthreads();
  float lacc = 0.f;
  {
    u32 av[13];
    *(uint4*)&av[0] = *(const uint4*)(aav);
    *(uint4*)&av[4] = *(const uint4*)(aav + 4);
    *(uint4*)&av[8] = *(const uint4*)(aav + 8);
    av[12] = aav[12];
    float e0 = 0.f, e1 = 0.f, e2 = 0.f;
#pragma unroll
    for (int d = 0; d < 3; ++d) {
      if (d < nr) {
        const u32* kc = KtT + (80*d + rg)*132 + cg*16;
        u32 kv[13];
        *(uint4*)&kv[0] = *(const uint4*)(kc);
        *(uint4*)&kv[4] = *(const uint4*)(kc + 4);
        *(uint4*)&kv[8] = *(const uint4*)(kc + 8);
        kv[12] = kc[12];
        float acc = 0.f;
#pragma unroll
        for (int k = 0; k < 13; ++k) acc = dot2bf(kv[k], av[k], acc);
        if (d == 0) e0 = acc; else if (d == 1) e1 = acc; else e2 = acc;
      }
    }
    e0 = swz_add<0x101F>(dpp_add<0x4E>(dpp_add<0xB1>(e0)));
    e1 = swz_add<0x101F>(dpp_add<0x4E>(dpp_add<0xB1>(e1)));
    e2 = swz_add<0x101F>(dpp_add<0x4E>(dpp_add<0xB1>(e2)));
    const float o0 = ordered_t[m*NN + rg];
    const float o1 = ordered_t[m*NN + 80 + rg];
    const float d0 = o0 - b0*e0;
    const float d1 = o1 - b1*e1;
    lacc = fmaf(d0, d0, d1*d1);
    if (nr3) {
      const float o2 = ordered_t[m*NN + 160 + rg];
      const float d2 = o2 - b2*e2;
      lacc = fmaf(d2, d2, lacc);
    }
    lacc = (cg == 0) ? lacc : 0.f;    // one count per column
  }
  lacc = dpp_add<0xB1>(lacc);
  lacc = dpp_add<0x4E>(lacc);
  lacc = swz_add<0x101F>(lacc);
  lacc = dpp_add<0x128>(lacc);
  lacc = pl16_add(lacc);
  lacc = pl32_add(lacc);
  if (lane == 0) wred[w] = lacc;
  __syncthreads();
  if (tid == 0) {
    float ssum = 0.f;
#pragma unroll
    for (int i = 0; i < 10; ++i) ssum += wred[i];
    atomicAdd(out, ssum * (1.0f / 512000.0f));
  }
}

extern "C" void kernel_launch(void* const* d_in, const int* in_sizes, int n_in,
                              void* d_out, int out_size, void* d_ws, size_t ws_size,
                              hipStream_t stream) {
  (void)in_sizes; (void)n_in; (void)ws_size; (void)out_size;
  const float* random_  = (const float*)d_in[0];
  const float* ordered  = (const float*)d_in[1];
  const float* random_t = (const float*)d_in[2];
  const float* gumbel   = (const float*)d_in[3];
  const float* W1 = (const float*)d_in[4];
  const float* b1 = (const float*)d_in[5];
  const float* W2 = (const float*)d_in[6];
  const float* b2 = (const float*)d_in[7];
  float* out = (float*)d_out;
  float* ws  = (float*)d_ws;   // needs 52,928 B

  const size_t smem = SM_U32 * sizeof(u32);  // 106,688 B
  hipFuncSetAttribute((const void*)sinkhorn_main,
                      hipFuncAttributeMaxDynamicSharedMemorySize, (int)smem);
  prep_kernel<<<1, 256, 0, stream>>>(W1, b1, W2, b2, ws);
  hipMemsetAsync(out, 0, sizeof(float), stream);
  sinkhorn_main<<<NMAT, 640, smem, stream>>>(random_, ordered, random_t, gumbel, ws, out);
}